// Round 8
// baseline (16696.689 us; speedup 1.0000x reference)
//
#include <hip/hip_runtime.h>
#include <math.h>

#define NB   32
#define TH   128
#define NL   6
#define DD   128
#define NH   4
#define DHD  32
#define TCAP 128
#define D3   384
#define D4   512

typedef _Float16 f16;
typedef _Float16 f16x2 __attribute__((ext_vector_type(2)));
typedef _Float16 f16x4 __attribute__((ext_vector_type(4)));
typedef _Float16 f16x8 __attribute__((ext_vector_type(8)));

// repacked [l][kp][c] f16x2-unit counts (unit = (w[2kp][c], w[2kp+1][c]))
#define UQ (NL * 64 * D3)
#define UP (NL * 64 * DD)
#define UF (NL * 64 * D4)
#define UG (NL * 256 * DD)
#define NUNITS (UQ + UP + UF + UG)
// S/T table layout (float2 per output column)
#define BQ 0
#define BP (NL * D3)
#define BF (BP + NL * DD)
#define BG (BF + NL * D4)
#define BH (BG + NL * DD)
#define NCOLS (BH + 1)
#define NCOLS_PAD 6914

#define BAR_LDS() asm volatile("s_waitcnt lgkmcnt(0)\n\ts_barrier" ::: "memory")
#define BAR_ALL() asm volatile("s_waitcnt vmcnt(0) lgkmcnt(0)\n\ts_barrier" ::: "memory")
#define WAVE_LDS_WAIT() asm volatile("s_waitcnt lgkmcnt(0)" ::: "memory")

// ---- prep: fold LN into weights, repack k-pair-interleaved, compute S/T ----
__global__ void prep(const float* __restrict__ qkv_w, const float* __restrict__ qkv_b,
                     const float* __restrict__ proj_w, const float* __restrict__ proj_b,
                     const float* __restrict__ fc_w,  const float* __restrict__ fc_b,
                     const float* __restrict__ fc2_w, const float* __restrict__ fc2_b,
                     const float* __restrict__ ln1w, const float* __restrict__ ln1b,
                     const float* __restrict__ ln2w, const float* __restrict__ ln2b,
                     const float* __restrict__ lnfw, const float* __restrict__ lnfb,
                     const float* __restrict__ head_w, const float* __restrict__ head_b,
                     f16* __restrict__ wf, f16* __restrict__ wh, float* __restrict__ st) {
    int u = blockIdx.x * blockDim.x + threadIdx.x;
    if (u < NUNITS) {
        f16x2* o2 = (f16x2*)wf;
        f16x2 w;
        if (u < UQ) {
            int l = u / (64 * D3), rel = u % (64 * D3), kp = rel / D3, c = rel % D3;
            w.x = (f16)(ln1w[l * DD + 2 * kp]     * qkv_w[((size_t)l * DD + 2 * kp)     * D3 + c]);
            w.y = (f16)(ln1w[l * DD + 2 * kp + 1] * qkv_w[((size_t)l * DD + 2 * kp + 1) * D3 + c]);
        } else if (u < UQ + UP) {
            int r = u - UQ, l = r / (64 * DD), rel = r % (64 * DD), kp = rel / DD, c = rel % DD;
            w.x = (f16)proj_w[((size_t)l * DD + 2 * kp)     * DD + c];
            w.y = (f16)proj_w[((size_t)l * DD + 2 * kp + 1) * DD + c];
        } else if (u < UQ + UP + UF) {
            int r = u - UQ - UP, l = r / (64 * D4), rel = r % (64 * D4), kp = rel / D4, c = rel % D4;
            w.x = (f16)(ln2w[l * DD + 2 * kp]     * fc_w[((size_t)l * DD + 2 * kp)     * D4 + c]);
            w.y = (f16)(ln2w[l * DD + 2 * kp + 1] * fc_w[((size_t)l * DD + 2 * kp + 1) * D4 + c]);
        } else {
            int r = u - UQ - UP - UF, l = r / (256 * DD), rel = r % (256 * DD), kp = rel / DD, c = rel % DD;
            w.x = (f16)fc2_w[((size_t)l * D4 + 2 * kp)     * DD + c];
            w.y = (f16)fc2_w[((size_t)l * D4 + 2 * kp + 1) * DD + c];
        }
        o2[u] = w;
        return;
    }
    int g = u - NUNITS;
    if (g >= NCOLS) return;
    float S = 0.f, T = 0.f;
    if (g < BP) {
        int l = g / D3, c = g % D3;
        for (int k = 0; k < DD; k++) {
            float wv = qkv_w[((size_t)l * DD + k) * D3 + c];
            S += ln1w[l * DD + k] * wv; T += ln1b[l * DD + k] * wv;
        }
        T += qkv_b[l * D3 + c];
    } else if (g < BF) {
        int g2 = g - BP; T = proj_b[g2];
    } else if (g < BG) {
        int g2 = g - BF, l = g2 / D4, c = g2 % D4;
        for (int k = 0; k < DD; k++) {
            float wv = fc_w[((size_t)l * DD + k) * D4 + c];
            S += ln2w[l * DD + k] * wv; T += ln2b[l * DD + k] * wv;
        }
        T += fc_b[l * D4 + c];
    } else if (g < BH) {
        int g2 = g - BG; T = fc2_b[g2];
    } else {
        for (int k = 0; k < DD; k++) {
            float wp = lnfw[k] * head_w[k];
            wh[k] = (f16)wp; S += wp; T += lnfb[k] * head_w[k];
        }
        T += head_b[0];
    }
    st[2 * g] = S; st[2 * g + 1] = T;
}

__device__ __forceinline__ float dotv(f16x8 a, f16x8 b, float acc) {
    acc = __builtin_amdgcn_fdot2((f16x2){a[0], a[1]}, (f16x2){b[0], b[1]}, acc, false);
    acc = __builtin_amdgcn_fdot2((f16x2){a[2], a[3]}, (f16x2){b[2], b[3]}, acc, false);
    acc = __builtin_amdgcn_fdot2((f16x2){a[4], a[5]}, (f16x2){b[4], b[5]}, acc, false);
    acc = __builtin_amdgcn_fdot2((f16x2){a[6], a[7]}, (f16x2){b[6], b[7]}, acc, false);
    return acc;
}
__device__ __forceinline__ void dot8(float* acc, f16x2 hp, f16x8 wa, f16x8 wb) {
    acc[0] = __builtin_amdgcn_fdot2(hp, (f16x2){wa[0], wa[1]}, acc[0], false);
    acc[1] = __builtin_amdgcn_fdot2(hp, (f16x2){wa[2], wa[3]}, acc[1], false);
    acc[2] = __builtin_amdgcn_fdot2(hp, (f16x2){wa[4], wa[5]}, acc[2], false);
    acc[3] = __builtin_amdgcn_fdot2(hp, (f16x2){wa[6], wa[7]}, acc[3], false);
    acc[4] = __builtin_amdgcn_fdot2(hp, (f16x2){wb[0], wb[1]}, acc[4], false);
    acc[5] = __builtin_amdgcn_fdot2(hp, (f16x2){wb[2], wb[3]}, acc[5], false);
    acc[6] = __builtin_amdgcn_fdot2(hp, (f16x2){wb[4], wb[5]}, acc[6], false);
    acc[7] = __builtin_amdgcn_fdot2(hp, (f16x2){wb[6], wb[7]}, acc[7], false);
}
__device__ __forceinline__ void stats(const float* xf, int lane, float& rs, float& mneg) {
    float v0 = xf[lane], v1 = xf[lane + 64];
    float sm = v0 + v1, sq = v0 * v0 + v1 * v1;
    #pragma unroll
    for (int o = 1; o < 64; o <<= 1) { sm += __shfl_xor(sm, o); sq += __shfl_xor(sq, o); }
    float m = sm * (1.f / DD);
    rs = rsqrtf(sq * (1.f / DD) - m * m + 1e-5f);
    mneg = -rs * m;
}
__device__ __forceinline__ float gelu_tanh(float v) {
    float t = v * v * v;
    return 0.5f * v * (1.f + tanhf(0.7978845608028654f * (v + 0.044715f * t)));
}

__global__ __launch_bounds__(512) void gpt_loop(
    const float* __restrict__ data, const float* __restrict__ r,
    const float* __restrict__ wte_w, const float* __restrict__ wte_b,
    const float* __restrict__ wpe,
    const f16* __restrict__ wf, const f16* __restrict__ wh,
    const float* __restrict__ st,
    f16* __restrict__ Kc, f16* __restrict__ Vc,
    float* __restrict__ Y)
{
    const int b = blockIdx.x, tid = threadIdx.x;
    const int lane = tid & 63, wv = tid >> 6;

    const f16x2* WQr = (const f16x2*)wf;
    const f16x2* WPr = WQr + UQ;
    const f16x2* WFr = WPr + UP;
    const f16x2* WGr = WFr + UF;

    __shared__ float xf[DD];
    __shared__ __align__(16) f16 xh[DD], o16[DD], hm[D4];
    __shared__ __align__(16) f16 qw[NH][DHD], kw[NH][DHD];
    __shared__ float p32[NH][TCAP];
    __shared__ float s_sh, u_sh;
    __shared__ float stl[2 * NCOLS];    // S/T cache (~55 KB)
    __shared__ __align__(16) f16 whl[DD];

    const float p0 = data[b * 2 + 0];
    const float p1 = data[b * 2 + 1];

    f16* Kb = Kc + (size_t)b * NL * TCAP * DD;   // [l][j][c] row-major
    f16* Vb = Vc + (size_t)b * NL * TCAP * DD;   // [l][j][c] row-major

    for (int idx = tid; idx < 2 * NCOLS; idx += 512) stl[idx] = st[idx];
    if (tid < DD) whl[tid] = wh[tid];
    if (tid == 0) { s_sh = 0.f; u_sh = 0.f; }
    __syncthreads();
    if (tid < DD) {   // embed step 0 (s=u=0)
        float e = r[b * TH + 0];
        float xv = e * wte_w[tid] + wte_b[tid] + wpe[tid];
        xf[tid] = xv; xh[tid] = (f16)xv;
    }
    BAR_LDS();

    for (int i = 0; i < TH; i++) {
        for (int l = 0; l < NL; l++) {
            // ---- Phase A: qkv (LN1 folded) + in-wave scores/softmax ----
            {
                const int cg = lane >> 3, ks = lane & 7;
                if (wv < 6) {
                    float rs, mneg; stats(xf, lane, rs, mneg);
                    int colu;
                    if (wv < 4) colu = (cg < 4) ? (wv * 32 + cg * 8)
                                                : (DD + wv * 32 + (cg - 4) * 8);
                    else        colu = 2 * DD + (wv - 4) * 64 + cg * 8;
                    const f16x2* W = WQr + (size_t)l * 64 * D3;
                    f16x8 xa = *(const f16x8*)(xh + ks * 16);
                    f16x8 xb = *(const f16x8*)(xh + ks * 16 + 8);
                    float acc[8] = {0,0,0,0,0,0,0,0};
                    #pragma unroll
                    for (int t = 0; t < 8; t++) {
                        int u0 = (ks * 8 + t) * D3 + colu;
                        f16x8 wa = *(const f16x8*)(W + u0);
                        f16x8 wb = *(const f16x8*)(W + u0 + 4);
                        f16x2 hp = (t < 4) ? (f16x2){xa[2*t], xa[2*t+1]}
                                           : (f16x2){xb[2*(t-4)], xb[2*(t-4)+1]};
                        dot8(acc, hp, wa, wb);
                    }
                    #pragma unroll
                    for (int off = 1; off <= 4; off <<= 1) {
                        #pragma unroll
                        for (int j = 0; j < 8; j++) acc[j] += __shfl_xor(acc[j], off);
                    }
                    if (ks == 0) {
                        const int gcol = l * D3 + colu;
                        f16x8 pk;
                        #pragma unroll
                        for (int j = 0; j < 8; j++)
                            pk[j] = (f16)(rs * acc[j] + mneg * stl[2*(gcol+j)] + stl[2*(gcol+j)+1]);
                        if (wv < 4) {
                            if (cg < 4) *(f16x8*)(&qw[wv][cg * 8]) = pk;
                            else { *(f16x8*)(&kw[wv][(cg - 4) * 8]) = pk;
                                   *(f16x8*)(Kb + ((size_t)l * TCAP + i) * DD + (colu - DD)) = pk; }
                        } else {
                            *(f16x8*)(Vb + ((size_t)l * TCAP + i) * DD + (colu - 2 * DD)) = pk;
                        }
                    }
                }
                if (wv < NH) {   // scores + softmax, in-wave
                    WAVE_LDS_WAIT();
                    const int h = wv;
                    const f16x8* qp = (const f16x8*)qw[h];
                    f16x8 q0 = qp[0], q1 = qp[1], q2 = qp[2], q3 = qp[3];
                    const int j0 = lane, j1 = lane + 64;
                    float sc0 = -1e30f, sc1 = -1e30f;
                    const f16* Kl = Kb + (size_t)l * TCAP * DD + h * DHD;
                    const float sscale = 0.17677669529663687f;
                    if (j0 <= i) {
                        const f16x8* Kj = (j0 == i) ? (const f16x8*)kw[h]
                                                    : (const f16x8*)(Kl + (size_t)j0 * DD);
                        float d = 0.f;
                        d = dotv(q0, Kj[0], d); d = dotv(q1, Kj[1], d);
                        d = dotv(q2, Kj[2], d); d = dotv(q3, Kj[3], d);
                        sc0 = d * sscale;
                    }
                    if (j1 <= i) {
                        const f16x8* Kj = (j1 == i) ? (const f16x8*)kw[h]
                                                    : (const f16x8*)(Kl + (size_t)j1 * DD);
                        float d = 0.f;
                        d = dotv(q0, Kj[0], d); d = dotv(q1, Kj[1], d);
                        d = dotv(q2, Kj[2], d); d = dotv(q3, Kj[3], d);
                        sc1 = d * sscale;
                    }
                    float mx = fmaxf(sc0, sc1);
                    #pragma unroll
                    for (int o = 1; o < 64; o <<= 1) mx = fmaxf(mx, __shfl_xor(mx, o));
                    float e0 = (j0 <= i) ? __expf(sc0 - mx) : 0.f;
                    float e1 = (j1 <= i) ? __expf(sc1 - mx) : 0.f;
                    float se = e0 + e1;
                    #pragma unroll
                    for (int o = 1; o < 64; o <<= 1) se += __shfl_xor(se, o);
                    float inv = 1.f / se;
                    p32[h][j0] = e0 * inv;
                    p32[h][j1] = e1 * inv;
                }
            }
            BAR_ALL();   // K/V row-i stores drained; q/k/p visible

            // ---- Phase B: AV, coalesced row-major V ----
            {
                const int c16 = lane & 15, js = lane >> 4;
                const int c = wv * 16 + c16, h = wv >> 1;
                const f16* vcol = Vb + (size_t)l * TCAP * DD + c;
                float a = 0.f;
                const int jlo = js * 32, jhi = min(i + 1, js * 32 + 32);
                for (int j = jlo; j < jhi; j++)
                    a += p32[h][j] * (float)vcol[(size_t)j * DD];
                a += __shfl_xor(a, 16);
                a += __shfl_xor(a, 32);
                if (lane < 16) o16[c] = (f16)a;
            }
            BAR_LDS();

            // ---- Phase C: attn proj + residual ----
            {
                const int cg = lane >> 5, ks = lane & 31;
                const int cb = wv * 16 + cg * 8;
                const f16x2* W = WPr + (size_t)l * 64 * DD;
                f16x4 oa = *(const f16x4*)(o16 + ks * 4);
                float acc[8] = {0,0,0,0,0,0,0,0};
                #pragma unroll
                for (int t = 0; t < 2; t++) {
                    int u0 = (ks * 2 + t) * DD + cb;
                    f16x8 wa = *(const f16x8*)(W + u0);
                    f16x8 wb = *(const f16x8*)(W + u0 + 4);
                    f16x2 hp = (f16x2){oa[2*t], oa[2*t+1]};
                    dot8(acc, hp, wa, wb);
                }
                #pragma unroll
                for (int off = 1; off <= 16; off <<= 1) {
                    #pragma unroll
                    for (int j = 0; j < 8; j++) acc[j] += __shfl_xor(acc[j], off);
                }
                if (ks == 0) {
                    const int gcol = BP + l * DD + cb;
                    #pragma unroll
                    for (int j = 0; j < 8; j++) {
                        float xv = xf[cb + j] + acc[j] + stl[2*(gcol+j)+1];
                        xf[cb + j] = xv; xh[cb + j] = (f16)xv;
                    }
                }
            }
            BAR_LDS();

            // ---- Phase D: fc (LN2 folded) + gelu ----
            {
                float rs, mneg; stats(xf, lane, rs, mneg);
                const int cg = lane >> 3, ks = lane & 7;
                const int cb = wv * 64 + cg * 8;
                const f16x2* W = WFr + (size_t)l * 64 * D4;
                f16x8 xa = *(const f16x8*)(xh + ks * 16);
                f16x8 xb = *(const f16x8*)(xh + ks * 16 + 8);
                float acc[8] = {0,0,0,0,0,0,0,0};
                #pragma unroll
                for (int t = 0; t < 8; t++) {
                    int u0 = (ks * 8 + t) * D4 + cb;
                    f16x8 wa = *(const f16x8*)(W + u0);
                    f16x8 wb = *(const f16x8*)(W + u0 + 4);
                    f16x2 hp = (t < 4) ? (f16x2){xa[2*t], xa[2*t+1]}
                                       : (f16x2){xb[2*(t-4)], xb[2*(t-4)+1]};
                    dot8(acc, hp, wa, wb);
                }
                #pragma unroll
                for (int off = 1; off <= 4; off <<= 1) {
                    #pragma unroll
                    for (int j = 0; j < 8; j++) acc[j] += __shfl_xor(acc[j], off);
                }
                if (ks == 0) {
                    const int gcol = BF + l * D4 + cb;
                    f16x8 pk;
                    #pragma unroll
                    for (int j = 0; j < 8; j++)
                        pk[j] = (f16)gelu_tanh(rs * acc[j] + mneg * stl[2*(gcol+j)] + stl[2*(gcol+j)+1]);
                    *(f16x8*)(hm + cb) = pk;
                }
            }
            BAR_LDS();

            // ---- Phase E: fc2 + residual ----
            {
                const int cg = lane >> 5, ks = lane & 31;
                const int cb = wv * 16 + cg * 8;
                const f16x2* W = WGr + (size_t)l * 256 * DD;
                f16x8 ha  = *(const f16x8*)(hm + ks * 16);
                f16x8 hb2 = *(const f16x8*)(hm + ks * 16 + 8);
                float acc[8] = {0,0,0,0,0,0,0,0};
                #pragma unroll
                for (int t = 0; t < 8; t++) {
                    int u0 = (ks * 8 + t) * DD + cb;
                    f16x8 wa = *(const f16x8*)(W + u0);
                    f16x8 wb = *(const f16x8*)(W + u0 + 4);
                    f16x2 hp = (t < 4) ? (f16x2){ha[2*t], ha[2*t+1]}
                                       : (f16x2){hb2[2*(t-4)], hb2[2*(t-4)+1]};
                    dot8(acc, hp, wa, wb);
                }
                #pragma unroll
                for (int off = 1; off <= 16; off <<= 1) {
                    #pragma unroll
                    for (int j = 0; j < 8; j++) acc[j] += __shfl_xor(acc[j], off);
                }
                if (ks == 0) {
                    const int gcol = BG + l * DD + cb;
                    #pragma unroll
                    for (int j = 0; j < 8; j++) {
                        float xv = xf[cb + j] + acc[j] + stl[2*(gcol+j)+1];
                        xf[cb + j] = xv; xh[cb + j] = (f16)xv;
                    }
                }
            }
            BAR_LDS();
        } // layers

        // ---- head (lnf folded) + state update ----
        if (wv == 0) {
            float rs, mneg; stats(xf, lane, rs, mneg);
            f16x2 xp = ((const f16x2*)xh)[lane];
            f16x2 wp = ((const f16x2*)whl)[lane];
            float d = __builtin_amdgcn_fdot2(xp, wp, 0.f, false);
            #pragma unroll
            for (int o = 1; o < 64; o <<= 1) d += __shfl_xor(d, o);
            if (lane == 0) {
                float u = rs * d + mneg * stl[2 * BH] + stl[2 * BH + 1];
                float s = s_sh;
                Y[b * TH + i] = s;
                s_sh = s + (-p0 * s + p1 * tanhf(u));
                u_sh = u;
            }
        }
        BAR_LDS();

        // ---- embed for step i+1 ----
        if (i + 1 < TH && tid < DD) {
            float e = r[b * TH + i + 1] - s_sh;
            float xv = e * wte_w[tid] + u_sh * wte_w[DD + tid] + wte_b[tid]
                     + wpe[(i + 1) * DD + tid];
            xf[tid] = xv; xh[tid] = (f16)xv;
        }
        BAR_LDS();
    } // steps
}

extern "C" void kernel_launch(void* const* d_in, const int* in_sizes, int n_in,
                              void* d_out, int out_size, void* d_ws, size_t ws_size,
                              hipStream_t stream) {
    const float* data   = (const float*)d_in[0];
    const float* r      = (const float*)d_in[1];
    const float* wte_w  = (const float*)d_in[2];
    const float* wte_b  = (const float*)d_in[3];
    const float* wpe    = (const float*)d_in[4];
    const float* ln1_w  = (const float*)d_in[5];
    const float* ln1_b  = (const float*)d_in[6];
    const float* ln2_w  = (const float*)d_in[7];
    const float* ln2_b  = (const float*)d_in[8];
    const float* qkv_w  = (const float*)d_in[9];
    const float* qkv_b  = (const float*)d_in[10];
    const float* proj_w = (const float*)d_in[11];
    const float* proj_b = (const float*)d_in[12];
    const float* fc_w   = (const float*)d_in[13];
    const float* fc_b   = (const float*)d_in[14];
    const float* fc2_w  = (const float*)d_in[15];
    const float* fc2_b  = (const float*)d_in[16];
    const float* lnf_w  = (const float*)d_in[17];
    const float* lnf_b  = (const float*)d_in[18];
    const float* head_w = (const float*)d_in[19];
    const float* head_b = (const float*)d_in[20];

    f16*   wfp = (f16*)d_ws;                       // 2*NUNITS f16
    f16*   whp = wfp + 2 * (size_t)NUNITS;         // 128 f16
    float* stp = (float*)(whp + DD);               // 2*NCOLS_PAD floats
    f16*   Kc  = (f16*)(stp + 2 * NCOLS_PAD);
    f16*   Vc  = Kc + (size_t)NB * NL * TCAP * DD;

    const int total = NUNITS + NCOLS;
    prep<<<(total + 255) / 256, 256, 0, stream>>>(
        qkv_w, qkv_b, proj_w, proj_b, fc_w, fc_b, fc2_w, fc2_b,
        ln1_w, ln1_b, ln2_w, ln2_b, lnf_w, lnf_b, head_w, head_b, wfp, whp, stp);

    gpt_loop<<<NB, 512, 0, stream>>>(
        data, r, wte_w, wte_b, wpe, wfp, whp, stp, Kc, Vc, (float*)d_out);
}